// Round 12
// baseline (2060.982 us; speedup 1.0000x reference)
//
#include <hip/hip_runtime.h>
#include <hip/hip_fp16.h>
#include <hip/hip_cooperative_groups.h>

namespace cg = cooperative_groups;

#define N_NODES 50000
#define N_EDGES 800000
#define CH 96
#define NSLICE 3            // channel slices of 32ch: one 64B line per (edge,slice)
#define SUBS 4              // 16B sub-chunks per 64B row
#define ROWB 64             // fully-packed row: 32ch * 2B = 64B
#define STEPS 10
#define SENT N_NODES        // sentinel src row (kept zero in every slice)
#define NDST_X 6250         // dst nodes per XCD range (50000/8) for setup dup
#define NBINS 64            // degree-sort bins (iters = padded_deg/4, clamped)
#define LANES_PER_SLICE (N_NODES * SUBS)          // 200000
#define NBLK_SLICE 782                            // ceil(200000/256)

#define SLICE3 3200256ull                         // align256((N_NODES+1)*ROWB)
#define SLAB (3ull * SLICE3)                      // one p_k, ~9.6MB

// ---------- CSR build (XCD-local atomics: 8x duplicated, dst-range partitioned) ----------

__global__ void count_deg(const int* __restrict__ ei, int* __restrict__ deg, int ne) {
    int xr = blockIdx.x & 7;
    int lo = xr * NDST_X, hi = lo + NDST_X;
    int t = (blockIdx.x >> 3) * 256 + threadIdx.x;
    int e = t * 4;
    if (e < ne) {
        int4 d4 = *(const int4*)(ei + ne + e);
        if (d4.x >= lo && d4.x < hi) atomicAdd(&deg[d4.x], 1);
        if (d4.y >= lo && d4.y < hi) atomicAdd(&deg[d4.y], 1);
        if (d4.z >= lo && d4.z < hi) atomicAdd(&deg[d4.z], 1);
        if (d4.w >= lo && d4.w < hi) atomicAdd(&deg[d4.w], 1);
    }
}

__global__ void scan1(const int* __restrict__ deg, int* __restrict__ row_ptr,
                      int* __restrict__ partials, float* __restrict__ dinv, int n) {
    __shared__ int sm[256];
    int i = blockIdx.x * 256 + threadIdx.x;
    int v = 0;
    if (i < n) {
        int d = deg[i];
        dinv[i] = (d > 0) ? (1.0f / sqrtf((float)d)) : 0.0f;
        v = (d + 3) & ~3;
    }
    sm[threadIdx.x] = v;
    __syncthreads();
    for (int off = 1; off < 256; off <<= 1) {
        int t = (threadIdx.x >= off) ? sm[threadIdx.x - off] : 0;
        __syncthreads();
        sm[threadIdx.x] += t;
        __syncthreads();
    }
    if (i < n) row_ptr[i + 1] = sm[threadIdx.x];
    if (threadIdx.x == 255) partials[blockIdx.x] = sm[255];
}

__global__ void scan2(int* __restrict__ partials, int nb) {
    __shared__ int sm[256];
    int v = (threadIdx.x < nb) ? partials[threadIdx.x] : 0;
    sm[threadIdx.x] = v;
    __syncthreads();
    for (int off = 1; off < 256; off <<= 1) {
        int t = (threadIdx.x >= off) ? sm[threadIdx.x - off] : 0;
        __syncthreads();
        sm[threadIdx.x] += t;
        __syncthreads();
    }
    if (threadIdx.x < nb) partials[threadIdx.x] = sm[threadIdx.x] - v;
}

__global__ void scan3(int* __restrict__ row_ptr, const int* __restrict__ partials, int n) {
    int i = blockIdx.x * 256 + threadIdx.x;
    if (i < n) row_ptr[i + 1] += partials[blockIdx.x];
    if (i == 0) row_ptr[0] = 0;
}

__global__ void pad_fill(const int* __restrict__ deg, const int* __restrict__ row_ptr,
                         unsigned short* __restrict__ cs, int n) {
    int i = blockIdx.x * blockDim.x + threadIdx.x;
    if (i < n) {
        int dg = deg[i];
        int dp = (dg + 3) & ~3;
        int base = row_ptr[i];
        for (int j = dg; j < dp; ++j) cs[base + j] = (unsigned short)SENT;
    }
}

__global__ void fill_csr(const int* __restrict__ ei, const int* __restrict__ row_ptr,
                         int* __restrict__ deg, unsigned short* __restrict__ cs, int ne) {
    int xr = blockIdx.x & 7;
    int lo = xr * NDST_X, hi = lo + NDST_X;
    int t = (blockIdx.x >> 3) * 256 + threadIdx.x;
    int e = t * 4;
    if (e < ne) {
        int4 s4 = *(const int4*)(ei + e);
        int4 d4 = *(const int4*)(ei + ne + e);
        #pragma unroll
        for (int j = 0; j < 4; ++j) {
            int s = (j == 0) ? s4.x : (j == 1) ? s4.y : (j == 2) ? s4.z : s4.w;
            int d = (j == 0) ? d4.x : (j == 1) ? d4.y : (j == 2) ? d4.z : d4.w;
            if (d < lo || d >= hi) continue;
            if ((unsigned)s >= (unsigned)N_NODES) s = SENT;
            int slot = atomicSub(&deg[d], 1) - 1;
            cs[row_ptr[d] + slot] = (unsigned short)s;
        }
    }
}

// ---------- degree sort (counting sort by iteration count) ----------

__global__ void hist_deg(const int* __restrict__ row_ptr, int* __restrict__ bins, int n) {
    __shared__ int lb_[NBINS];
    if (threadIdx.x < NBINS) lb_[threadIdx.x] = 0;
    __syncthreads();
    int i = blockIdx.x * 256 + threadIdx.x;
    if (i < n) {
        int it = (row_ptr[i + 1] - row_ptr[i]) >> 2;
        atomicAdd(&lb_[it < NBINS ? it : NBINS - 1], 1);
    }
    __syncthreads();
    if (threadIdx.x < NBINS && lb_[threadIdx.x]) atomicAdd(&bins[threadIdx.x], lb_[threadIdx.x]);
}

__global__ void scan_bins(const int* __restrict__ bins, int* __restrict__ binptr) {
    __shared__ int sm[NBINS];
    int v = bins[threadIdx.x];
    sm[threadIdx.x] = v;
    __syncthreads();
    for (int off = 1; off < NBINS; off <<= 1) {
        int t = (threadIdx.x >= off) ? sm[threadIdx.x - off] : 0;
        __syncthreads();
        sm[threadIdx.x] += t;
        __syncthreads();
    }
    binptr[threadIdx.x] = sm[threadIdx.x] - v;   // exclusive
}

__global__ void scatter_order(const int* __restrict__ row_ptr, int* __restrict__ binptr,
                              int* __restrict__ order, int n) {
    int i = blockIdx.x * 256 + threadIdx.x;
    if (i < n) {
        int it = (row_ptr[i + 1] - row_ptr[i]) >> 2;
        int pos = atomicAdd(&binptr[it < NBINS ? it : NBINS - 1], 1);
        order[pos] = i;
    }
}

// ---------- prescale (+ sentinel zeroing fused) ----------

__global__ __launch_bounds__(256) void prescale16(const float* __restrict__ x,
                                                  const float* __restrict__ dinv,
                                                  char* __restrict__ p0, int nbuf) {
    int idx = blockIdx.x * 256 + threadIdx.x;
    const int nmain = NSLICE * LANES_PER_SLICE;
    if (idx < nmain) {
        int slice = idx / LANES_PER_SLICE;
        int rem   = idx - slice * LANES_PER_SLICE;
        int node  = rem >> 2;
        int sub   = rem & 3;
        float dv = dinv[node];
        const float4* xb = (const float4*)((const char*)x + (size_t)node * 384 + slice * 128 + sub * 32);
        float4 x0 = xb[0], x1 = xb[1];
        uint4 q;
        ((__half2*)&q)[0] = __floats2half2_rn(dv * x0.x, dv * x0.y);
        ((__half2*)&q)[1] = __floats2half2_rn(dv * x0.z, dv * x0.w);
        ((__half2*)&q)[2] = __floats2half2_rn(dv * x1.x, dv * x1.y);
        ((__half2*)&q)[3] = __floats2half2_rn(dv * x1.z, dv * x1.w);
        *(uint4*)(p0 + (size_t)slice * SLICE3 + (size_t)node * ROWB + sub * 16) = q;
    } else if (idx < nmain + nbuf * NSLICE * SUBS) {
        int t = idx - nmain;
        int sub   = t & 3;
        int slice = (t >> 2) % NSLICE;
        int buf   = t / (SUBS * NSLICE);
        uint4 z = {0u, 0u, 0u, 0u};
        *(uint4*)(p0 + (size_t)buf * SLAB + (size_t)slice * SLICE3
                  + (size_t)SENT * ROWB + sub * 16) = z;
    }
}

__device__ inline void acc8(float* a, uint4 q) {
    const __half2* h = (const __half2*)&q;
    #pragma unroll
    for (int i = 0; i < 4; ++i) {
        float2 f = __half22float2(h[i]);
        a[2 * i] += f.x; a[2 * i + 1] += f.y;
    }
}

// one step of the gather for one (slice, node, sub) lane
__device__ inline void prop_lane(const char* pin_s, char* pout_s,
                                 const int* __restrict__ row_ptr,
                                 const unsigned short* __restrict__ cs,
                                 const float* __restrict__ dinv, int node, int sub) {
    const char* pin = pin_s + sub * 16;
    int beg = row_ptr[node];
    int end = row_ptr[node + 1];                  // multiple of 4
    float acc[8] = {0.f, 0.f, 0.f, 0.f, 0.f, 0.f, 0.f, 0.f};
    for (int e = beg; e < end; e += 4) {
        ushort4 m = *(const ushort4*)(cs + e);
        uint4 q0 = *(const uint4*)(pin + (size_t)m.x * ROWB);
        uint4 q1 = *(const uint4*)(pin + (size_t)m.y * ROWB);
        uint4 q2 = *(const uint4*)(pin + (size_t)m.z * ROWB);
        uint4 q3 = *(const uint4*)(pin + (size_t)m.w * ROWB);
        acc8(acc, q0);
        acc8(acc, q1);
        acc8(acc, q2);
        acc8(acc, q3);
    }
    float dv = dinv[node];
    float s = dv * dv;                            // p_out = fp16(dinv^2 * S)
    uint4 q;
    ((__half2*)&q)[0] = __floats2half2_rn(s * acc[0], s * acc[1]);
    ((__half2*)&q)[1] = __floats2half2_rn(s * acc[2], s * acc[3]);
    ((__half2*)&q)[2] = __floats2half2_rn(s * acc[4], s * acc[5]);
    ((__half2*)&q)[3] = __floats2half2_rn(s * acc[6], s * acc[7]);
    *(uint4*)(pout_s + (size_t)node * ROWB + sub * 16) = q;
}

// finalize one (slice, node, sub) lane: out = gamma0*x + sum_k gamma_k*(p_k/dinv)
__device__ inline void finalize_lane(const char* __restrict__ p_base,
                                     const float* __restrict__ x,
                                     const float* __restrict__ dinv,
                                     const float* __restrict__ gamma,
                                     float* __restrict__ out, int slice, int node, int sub) {
    float dv  = dinv[node];
    float rdv = (dv > 0.f) ? (1.f / dv) : 0.f;
    const float4* xb = (const float4*)((const char*)x + (size_t)node * 384 + slice * 128 + sub * 32);
    float4 x0 = xb[0], x1 = xb[1];
    float g0 = gamma[0];
    float o[8] = {g0 * x0.x, g0 * x0.y, g0 * x0.z, g0 * x0.w,
                  g0 * x1.x, g0 * x1.y, g0 * x1.z, g0 * x1.w};
    const char* p = p_base + SLAB + (size_t)slice * SLICE3 + (size_t)node * ROWB + sub * 16;
    for (int k = 1; k <= STEPS; ++k) {
        uint4 q = *(const uint4*)p;
        p += SLAB;
        float gk = gamma[k] * rdv;
        const __half2* h = (const __half2*)&q;
        #pragma unroll
        for (int i = 0; i < 4; ++i) {
            float2 f = __half22float2(h[i]);
            o[2 * i]     = fmaf(gk, f.x, o[2 * i]);
            o[2 * i + 1] = fmaf(gk, f.y, o[2 * i + 1]);
        }
    }
    float4* ob = (float4*)((char*)out + (size_t)node * 384 + slice * 128 + sub * 32);
    ob[0] = make_float4(o[0], o[1], o[2], o[3]);
    ob[1] = make_float4(o[4], o[5], o[6], o[7]);
}

// XCD group -> slice mapping (groups {0,1,2}->s0, {3,4,5}->s1, {6,7}->s2)
__device__ inline void xcd_map(int xcd, int& slice, int& pos, int& gsz) {
    if (xcd < 3)      { slice = 0; pos = xcd;     gsz = 3; }
    else if (xcd < 6) { slice = 1; pos = xcd - 3; gsz = 3; }
    else              { slice = 2; pos = xcd - 6; gsz = 2; }
}

// ---------- fused persistent kernel: 10 prop steps + finalize ----------

__global__ __launch_bounds__(256) void prop_fused(char* __restrict__ p_base,
                                                  float* __restrict__ out,
                                                  const float* __restrict__ x,
                                                  const int* __restrict__ row_ptr,
                                                  const int* __restrict__ order,
                                                  const unsigned short* __restrict__ cs,
                                                  const float* __restrict__ dinv,
                                                  const float* __restrict__ gamma) {
    cg::grid_group gg = cg::this_grid();
    int xcd = blockIdx.x & 7;
    int r   = blockIdx.x >> 3;
    int rounds8 = gridDim.x >> 3;
    int slice, pos, gsz;
    xcd_map(xcd, slice, pos, gsz);
    int stride = gsz * rounds8;

    for (int k = 0; k < STEPS; ++k) {
        const char* pin_s = p_base + (size_t)k * SLAB + (size_t)slice * SLICE3;
        char* pout_s      = p_base + (size_t)(k + 1) * SLAB + (size_t)slice * SLICE3;
        for (int lb = r * gsz + pos; lb < NBLK_SLICE; lb += stride) {
            int t = lb * 256 + (int)threadIdx.x;
            if (t < LANES_PER_SLICE)
                prop_lane(pin_s, pout_s, row_ptr, cs, dinv, order[t >> 2], t & 3);
        }
        gg.sync();
    }
    for (int lb = r * gsz + pos; lb < NBLK_SLICE; lb += stride) {
        int t = lb * 256 + (int)threadIdx.x;
        if (t < LANES_PER_SLICE)
            finalize_lane(p_base, x, dinv, gamma, out, slice, t >> 2, t & 3);
    }
}

// ---------- fallback (non-cooperative) kernels ----------

__global__ __launch_bounds__(256) void prop16(const char* __restrict__ pin_slab,
                                              char* __restrict__ pout_slab,
                                              const int* __restrict__ row_ptr,
                                              const int* __restrict__ order,
                                              const unsigned short* __restrict__ cs,
                                              const float* __restrict__ dinv) {
    int xcd = blockIdx.x & 7;
    int r   = blockIdx.x >> 3;
    int rounds8 = gridDim.x >> 3;
    int slice, pos, gsz;
    xcd_map(xcd, slice, pos, gsz);
    int stride = gsz * rounds8;
    for (int lb = r * gsz + pos; lb < NBLK_SLICE; lb += stride) {
        int t = lb * 256 + (int)threadIdx.x;
        if (t < LANES_PER_SLICE)
            prop_lane(pin_slab + (size_t)slice * SLICE3,
                      pout_slab + (size_t)slice * SLICE3,
                      row_ptr, cs, dinv, order[t >> 2], t & 3);
    }
}

__global__ __launch_bounds__(256) void finalize(const char* __restrict__ p_base,
                                                const float* __restrict__ x,
                                                const float* __restrict__ dinv,
                                                const float* __restrict__ gamma,
                                                float* __restrict__ out) {
    int idx = blockIdx.x * 256 + threadIdx.x;
    if (idx >= NSLICE * LANES_PER_SLICE) return;
    int slice = idx / LANES_PER_SLICE;
    int rem   = idx - slice * LANES_PER_SLICE;
    finalize_lane(p_base, x, dinv, gamma, out, slice, rem >> 2, rem & 3);
}

// ---------- launch ----------

static inline size_t align_up(size_t v, size_t a) { return (v + a - 1) & ~(a - 1); }

extern "C" void kernel_launch(void* const* d_in, const int* in_sizes, int n_in,
                              void* d_out, int out_size, void* d_ws, size_t ws_size,
                              hipStream_t stream) {
    const float* x     = (const float*)d_in[0];
    const int*   ei    = (const int*)d_in[1];
    const float* gamma = (const float*)d_in[2];
    float*       out   = (float*)d_out;

    const int n  = N_NODES;
    const int ne = N_EDGES;
    const int nblk_nodes = (n + 255) / 256;          // 196
    const int ne_pad_max = ne + 4 * n;               // padded CSR capacity (1.0M)

    char*  ws  = (char*)d_ws;
    size_t off = 0;
    int*   deg      = (int*)(ws + off);   off = align_up(off + (size_t)n * 4, 256);
    int*   bins     = (int*)(ws + off);   off = align_up(off + NBINS * 4, 256);
    size_t zero_end = off;                            // memset deg..bins in one shot
    int*   binptr   = (int*)(ws + off);   off = align_up(off + NBINS * 4, 256);
    int*   row_ptr  = (int*)(ws + off);   off = align_up(off + (size_t)(n + 1) * 4, 256);
    int*   partials = (int*)(ws + off);   off = align_up(off + (size_t)nblk_nodes * 4, 256);
    float* dinv     = (float*)(ws + off); off = align_up(off + (size_t)n * 4, 256);
    int*   order    = (int*)(ws + off);   off = align_up(off + (size_t)n * 4, 256);
    unsigned short* cs = (unsigned short*)(ws + off);
    off = align_up(off + (size_t)ne_pad_max * 2, 256);
    char*  p_base   = ws + off;

    const bool deferred = (ws_size >= off + 11ull * SLAB);   // ~108MB needed
    const int  nbuf     = deferred ? 11 : 2;

    (void)hipMemsetAsync(deg, 0, zero_end, stream);   // deg + bins

    const int nblk_e4 = (ne / 4 + 255) / 256;        // 782 edge-chunk blocks
    count_deg<<<8 * nblk_e4, 256, 0, stream>>>(ei, deg, ne);

    scan1<<<nblk_nodes, 256, 0, stream>>>(deg, row_ptr, partials, dinv, n);
    scan2<<<1, 256, 0, stream>>>(partials, nblk_nodes);
    scan3<<<nblk_nodes, 256, 0, stream>>>(row_ptr, partials, n);

    // degree sort (order[] = node ids ascending by padded-degree)
    hist_deg<<<nblk_nodes, 256, 0, stream>>>(row_ptr, bins, n);
    scan_bins<<<1, NBINS, 0, stream>>>(bins, binptr);
    scatter_order<<<nblk_nodes, 256, 0, stream>>>(row_ptr, binptr, order, n);

    pad_fill<<<nblk_nodes, 256, 0, stream>>>(deg, row_ptr, cs, n);
    fill_csr<<<8 * nblk_e4, 256, 0, stream>>>(ei, row_ptr, deg, cs, ne);

    const int nlin = NSLICE * LANES_PER_SLICE + nbuf * NSLICE * SUBS;
    const int nblk_lin = (nlin + 255) / 256;
    prescale16<<<nblk_lin, 256, 0, stream>>>(x, dinv, p_base, nbuf);

    bool coop_done = false;
    if (deferred) {
        int nb = 0;
        if (hipOccupancyMaxActiveBlocksPerMultiprocessor(&nb, prop_fused, 256, 0) == hipSuccess && nb > 0) {
            long cap = (long)nb * 256;               // 256 CUs on MI355X
            int grid = (int)((cap / 8) * 8);
            if (grid > 8 * 261) grid = 8 * 261;      // 261 rounds covers all chunks (slice0: 3*261=783)
            if (grid >= 8) {
                char* pb = p_base; float* o = out;
                const float* xx = x; const int* rp = row_ptr; const int* od = order;
                const unsigned short* c = cs; const float* dv = dinv; const float* gm = gamma;
                void* args[] = {&pb, &o, &xx, &rp, &od, &c, &dv, &gm};
                if (hipLaunchCooperativeKernel(prop_fused, dim3(grid), dim3(256),
                                               args, 0, stream) == hipSuccess)
                    coop_done = true;
            }
        }
    }

    if (!coop_done) {
        const int PROP_GRID = 8 * 391;               // non-fused grid (covers slice2 on 2 XCDs)
        for (int k = 0; k < STEPS; ++k) {
            const char* pin  = p_base + (size_t)k * SLAB;
            char*       pout = p_base + (size_t)(k + 1) * SLAB;
            prop16<<<PROP_GRID, 256, 0, stream>>>(pin, pout, row_ptr, order, cs, dinv);
        }
        const int nfin = NSLICE * LANES_PER_SLICE;
        finalize<<<(nfin + 255) / 256, 256, 0, stream>>>(p_base, x, dinv, gamma, out);
    }
}

// Round 13
// 693.714 us; speedup vs baseline: 2.9709x; 2.9709x over previous
//
#include <hip/hip_runtime.h>
#include <hip/hip_fp16.h>

#define N_NODES 50000
#define N_EDGES 800000
#define NSLICE 3            // channel slices of 32ch: one 64B line per (edge,slice)
#define SUBS 4              // 16B sub-chunks per 64B row
#define ROWB 64             // fully-packed row: 32ch * 2B = 64B
#define STEPS 10
#define SENT N_NODES        // sentinel row id in NEW space (kept zero in every slice)
#define NDST_X 6250         // NEW-id range per XCD for fill partition (50000/8)
#define NBINS 64            // degree-sort bins (iters = padded_deg/4, clamped)
#define LANES_PER_SLICE (N_NODES * SUBS)          // 200000
#define NBLK_SLICE 782                            // ceil(200000/256)

#define SLICE3 3200256ull                         // align256((N_NODES+1)*ROWB)
#define SLAB (3ull * SLICE3)                      // one p_k, ~9.6MB

// ---------- degree count (8x duplicated, OLD-dst-range partitioned atomics) ----------

__global__ void count_deg(const int* __restrict__ ei, int* __restrict__ deg, int ne) {
    int xr = blockIdx.x & 7;
    int lo = xr * NDST_X, hi = lo + NDST_X;
    int t = (blockIdx.x >> 3) * 256 + threadIdx.x;
    int e = t * 4;
    if (e < ne) {
        int4 d4 = *(const int4*)(ei + ne + e);
        if (d4.x >= lo && d4.x < hi) atomicAdd(&deg[d4.x], 1);
        if (d4.y >= lo && d4.y < hi) atomicAdd(&deg[d4.y], 1);
        if (d4.z >= lo && d4.z < hi) atomicAdd(&deg[d4.z], 1);
        if (d4.w >= lo && d4.w < hi) atomicAdd(&deg[d4.w], 1);
    }
}

// ---------- degree sort: counting sort by padded-degree -> node renumbering ----------

__global__ void hist_deg(const int* __restrict__ deg, int* __restrict__ bins, int n) {
    __shared__ int lb_[NBINS];
    if (threadIdx.x < NBINS) lb_[threadIdx.x] = 0;
    __syncthreads();
    int i = blockIdx.x * 256 + threadIdx.x;
    if (i < n) {
        int it = (deg[i] + 3) >> 2;
        atomicAdd(&lb_[it < NBINS ? it : NBINS - 1], 1);
    }
    __syncthreads();
    if (threadIdx.x < NBINS && lb_[threadIdx.x]) atomicAdd(&bins[threadIdx.x], lb_[threadIdx.x]);
}

__global__ void scan_bins(const int* __restrict__ bins, int* __restrict__ binptr) {
    __shared__ int sm[NBINS];
    int v = bins[threadIdx.x];
    sm[threadIdx.x] = v;
    __syncthreads();
    for (int off = 1; off < NBINS; off <<= 1) {
        int t = (threadIdx.x >= off) ? sm[threadIdx.x - off] : 0;
        __syncthreads();
        sm[threadIdx.x] += t;
        __syncthreads();
    }
    binptr[threadIdx.x] = sm[threadIdx.x] - v;   // exclusive
}

// order[new]=old, newid16[old]=new, dinvN[new]=rsqrt(deg[old])
__global__ void scatter_order(const int* __restrict__ deg, int* __restrict__ binptr,
                              int* __restrict__ order, unsigned short* __restrict__ newid16,
                              float* __restrict__ dinvN, int n) {
    int i = blockIdx.x * 256 + threadIdx.x;
    if (i < n) {
        int d = deg[i];
        int it = (d + 3) >> 2;
        int pos = atomicAdd(&binptr[it < NBINS ? it : NBINS - 1], 1);
        order[pos] = i;
        newid16[i] = (unsigned short)pos;
        dinvN[pos] = (d > 0) ? (1.0f / sqrtf((float)d)) : 0.0f;
    }
}

// row_ptr over NEW order (padded degrees); cursor[new] = unpadded degree
__global__ void scan1N(const int* __restrict__ deg, const int* __restrict__ order,
                       int* __restrict__ row_ptr, int* __restrict__ partials,
                       int* __restrict__ cursor, int n) {
    __shared__ int sm[256];
    int i = blockIdx.x * 256 + threadIdx.x;
    int v = 0;
    if (i < n) {
        int dg = deg[order[i]];
        cursor[i] = dg;
        v = (dg + 3) & ~3;
    }
    sm[threadIdx.x] = v;
    __syncthreads();
    for (int off = 1; off < 256; off <<= 1) {
        int t = (threadIdx.x >= off) ? sm[threadIdx.x - off] : 0;
        __syncthreads();
        sm[threadIdx.x] += t;
        __syncthreads();
    }
    if (i < n) row_ptr[i + 1] = sm[threadIdx.x];
    if (threadIdx.x == 255) partials[blockIdx.x] = sm[255];
}

__global__ void scan2(int* __restrict__ partials, int nb) {
    __shared__ int sm[256];
    int v = (threadIdx.x < nb) ? partials[threadIdx.x] : 0;
    sm[threadIdx.x] = v;
    __syncthreads();
    for (int off = 1; off < 256; off <<= 1) {
        int t = (threadIdx.x >= off) ? sm[threadIdx.x - off] : 0;
        __syncthreads();
        sm[threadIdx.x] += t;
        __syncthreads();
    }
    if (threadIdx.x < nb) partials[threadIdx.x] = sm[threadIdx.x] - v;
}

__global__ void scan3(int* __restrict__ row_ptr, const int* __restrict__ partials, int n) {
    int i = blockIdx.x * 256 + threadIdx.x;
    if (i < n) row_ptr[i + 1] += partials[blockIdx.x];
    if (i == 0) row_ptr[0] = 0;
}

// fill pad slots [deg, deg_padded) with sentinel BEFORE fill_csr consumes cursor
__global__ void pad_fillN(const int* __restrict__ cursor, const int* __restrict__ row_ptr,
                          unsigned short* __restrict__ cs, int n) {
    int i = blockIdx.x * blockDim.x + threadIdx.x;
    if (i < n) {
        int dg = cursor[i];
        int dp = (dg + 3) & ~3;
        int base = row_ptr[i];
        for (int j = dg; j < dp; ++j) cs[base + j] = (unsigned short)SENT;
    }
}

// scatter NEW src ids into NEW-dst-grouped slots; 8x dup partitioned by NEW dst range
__global__ void fill_csrN(const int* __restrict__ ei, const int* __restrict__ row_ptr,
                          int* __restrict__ cursor, const unsigned short* __restrict__ newid16,
                          unsigned short* __restrict__ cs, int ne) {
    int xr = blockIdx.x & 7;
    int lo = xr * NDST_X, hi = lo + NDST_X;
    int t = (blockIdx.x >> 3) * 256 + threadIdx.x;
    int e = t * 4;
    if (e < ne) {
        int4 s4 = *(const int4*)(ei + e);
        int4 d4 = *(const int4*)(ei + ne + e);
        #pragma unroll
        for (int j = 0; j < 4; ++j) {
            int s = (j == 0) ? s4.x : (j == 1) ? s4.y : (j == 2) ? s4.z : s4.w;
            int d = (j == 0) ? d4.x : (j == 1) ? d4.y : (j == 2) ? d4.z : d4.w;
            if ((unsigned)d >= (unsigned)N_NODES) continue;
            int nd = newid16[d];
            if (nd < lo || nd >= hi) continue;
            unsigned short ns = ((unsigned)s >= (unsigned)N_NODES)
                                ? (unsigned short)SENT : newid16[s];
            int slot = atomicSub(&cursor[nd], 1) - 1;
            cs[row_ptr[nd] + slot] = ns;
        }
    }
}

// ---------- prescale into NEW layout (+ sentinel zeroing fused) ----------

__global__ __launch_bounds__(256) void prescale16N(const float* __restrict__ x,
                                                   const float* __restrict__ dinvN,
                                                   const int* __restrict__ order,
                                                   char* __restrict__ p0, int nbuf) {
    int idx = blockIdx.x * 256 + threadIdx.x;
    const int nmain = NSLICE * LANES_PER_SLICE;
    if (idx < nmain) {
        int slice = idx / LANES_PER_SLICE;
        int rem   = idx - slice * LANES_PER_SLICE;
        int node  = rem >> 2;                      // NEW id
        int sub   = rem & 3;
        int oldid = order[node];
        float dv = dinvN[node];
        const float4* xb = (const float4*)((const char*)x + (size_t)oldid * 384 + slice * 128 + sub * 32);
        float4 x0 = xb[0], x1 = xb[1];
        uint4 q;
        ((__half2*)&q)[0] = __floats2half2_rn(dv * x0.x, dv * x0.y);
        ((__half2*)&q)[1] = __floats2half2_rn(dv * x0.z, dv * x0.w);
        ((__half2*)&q)[2] = __floats2half2_rn(dv * x1.x, dv * x1.y);
        ((__half2*)&q)[3] = __floats2half2_rn(dv * x1.z, dv * x1.w);
        *(uint4*)(p0 + (size_t)slice * SLICE3 + (size_t)node * ROWB + sub * 16) = q;
    } else if (idx < nmain + nbuf * NSLICE * SUBS) {
        int t = idx - nmain;
        int sub   = t & 3;
        int slice = (t >> 2) % NSLICE;
        int buf   = t / (SUBS * NSLICE);
        uint4 z = {0u, 0u, 0u, 0u};
        *(uint4*)(p0 + (size_t)buf * SLAB + (size_t)slice * SLICE3
                  + (size_t)SENT * ROWB + sub * 16) = z;
    }
}

__device__ inline void acc8(float* a, uint4 q) {
    const __half2* h = (const __half2*)&q;
    #pragma unroll
    for (int i = 0; i < 4; ++i) {
        float2 f = __half22float2(h[i]);
        a[2 * i] += f.x; a[2 * i + 1] += f.y;
    }
}

// XCD group -> slice mapping (groups {0,1,2}->s0, {3,4,5}->s1, {6,7}->s2)
__device__ inline void xcd_map(int xcd, int& slice, int& pos, int& gsz) {
    if (xcd < 3)      { slice = 0; pos = xcd;     gsz = 3; }
    else if (xcd < 6) { slice = 1; pos = xcd - 3; gsz = 3; }
    else              { slice = 2; pos = xcd - 6; gsz = 2; }
}

// ---------- propagation (NEW id space: no indirection, degree-uniform waves) ----------
// Chunks processed in REVERSE order so highest-degree (last) chunks start first.
__global__ __launch_bounds__(256) void prop16(const char* __restrict__ pin_slab,
                                              char* __restrict__ pout_slab,
                                              const int* __restrict__ row_ptr,
                                              const unsigned short* __restrict__ cs,
                                              const float* __restrict__ dinvN) {
    int xcd = blockIdx.x & 7;
    int r   = blockIdx.x >> 3;
    int rounds8 = gridDim.x >> 3;
    int slice, pos, gsz;
    xcd_map(xcd, slice, pos, gsz);
    int stride = gsz * rounds8;
    const char* pin_s = pin_slab + (size_t)slice * SLICE3;
    char* pout_s      = pout_slab + (size_t)slice * SLICE3;

    for (int lb = r * gsz + pos; lb < NBLK_SLICE; lb += stride) {
        int chunk = NBLK_SLICE - 1 - lb;              // high-degree chunks first
        int t = chunk * 256 + (int)threadIdx.x;
        if (t >= LANES_PER_SLICE) continue;
        int node = t >> 2;
        int sub  = t & 3;

        const char* pin = pin_s + sub * 16;
        int beg = row_ptr[node];
        int end = row_ptr[node + 1];                  // multiple of 4
        float acc[8] = {0.f, 0.f, 0.f, 0.f, 0.f, 0.f, 0.f, 0.f};
        for (int e = beg; e < end; e += 4) {
            ushort4 m = *(const ushort4*)(cs + e);
            uint4 q0 = *(const uint4*)(pin + (size_t)m.x * ROWB);
            uint4 q1 = *(const uint4*)(pin + (size_t)m.y * ROWB);
            uint4 q2 = *(const uint4*)(pin + (size_t)m.z * ROWB);
            uint4 q3 = *(const uint4*)(pin + (size_t)m.w * ROWB);
            acc8(acc, q0);
            acc8(acc, q1);
            acc8(acc, q2);
            acc8(acc, q3);
        }
        float dv = dinvN[node];
        float s = dv * dv;                            // p_out = fp16(dinv^2 * S)
        uint4 q;
        ((__half2*)&q)[0] = __floats2half2_rn(s * acc[0], s * acc[1]);
        ((__half2*)&q)[1] = __floats2half2_rn(s * acc[2], s * acc[3]);
        ((__half2*)&q)[2] = __floats2half2_rn(s * acc[4], s * acc[5]);
        ((__half2*)&q)[3] = __floats2half2_rn(s * acc[6], s * acc[7]);
        *(uint4*)(pout_s + (size_t)node * ROWB + sub * 16) = q;
    }
}

// deferred: out[old] = gamma0*x[old] + sum_k gamma_k * (p_k[new] / dinv)
__global__ __launch_bounds__(256) void finalizeN(const char* __restrict__ p_base,
                                                 const float* __restrict__ x,
                                                 const float* __restrict__ dinvN,
                                                 const int* __restrict__ order,
                                                 const float* __restrict__ gamma,
                                                 float* __restrict__ out) {
    int idx = blockIdx.x * 256 + threadIdx.x;
    if (idx >= NSLICE * LANES_PER_SLICE) return;
    int slice = idx / LANES_PER_SLICE;
    int rem   = idx - slice * LANES_PER_SLICE;
    int node  = rem >> 2;                      // NEW id
    int sub   = rem & 3;
    int oldid = order[node];
    float dv  = dinvN[node];
    float rdv = (dv > 0.f) ? (1.f / dv) : 0.f;

    const float4* xb = (const float4*)((const char*)x + (size_t)oldid * 384 + slice * 128 + sub * 32);
    float4 x0 = xb[0], x1 = xb[1];
    float g0 = gamma[0];
    float o[8] = {g0 * x0.x, g0 * x0.y, g0 * x0.z, g0 * x0.w,
                  g0 * x1.x, g0 * x1.y, g0 * x1.z, g0 * x1.w};

    const char* p = p_base + SLAB + (size_t)slice * SLICE3 + (size_t)node * ROWB + sub * 16;
    for (int k = 1; k <= STEPS; ++k) {
        uint4 q = *(const uint4*)p;
        p += SLAB;
        float gk = gamma[k] * rdv;
        const __half2* h = (const __half2*)&q;
        #pragma unroll
        for (int i = 0; i < 4; ++i) {
            float2 f = __half22float2(h[i]);
            o[2 * i]     = fmaf(gk, f.x, o[2 * i]);
            o[2 * i + 1] = fmaf(gk, f.y, o[2 * i + 1]);
        }
    }
    float4* ob = (float4*)((char*)out + (size_t)oldid * 384 + slice * 128 + sub * 32);
    ob[0] = make_float4(o[0], o[1], o[2], o[3]);
    ob[1] = make_float4(o[4], o[5], o[6], o[7]);
}

// ---------- launch ----------

static inline size_t align_up(size_t v, size_t a) { return (v + a - 1) & ~(a - 1); }

extern "C" void kernel_launch(void* const* d_in, const int* in_sizes, int n_in,
                              void* d_out, int out_size, void* d_ws, size_t ws_size,
                              hipStream_t stream) {
    const float* x     = (const float*)d_in[0];
    const int*   ei    = (const int*)d_in[1];
    const float* gamma = (const float*)d_in[2];
    float*       out   = (float*)d_out;

    const int n  = N_NODES;
    const int ne = N_EDGES;
    const int nblk_nodes = (n + 255) / 256;          // 196
    const int ne_pad_max = ne + 4 * n;               // padded CSR capacity (1.0M)

    char*  ws  = (char*)d_ws;
    size_t off = 0;
    int*   deg      = (int*)(ws + off);   off = align_up(off + (size_t)n * 4, 256);
    int*   bins     = (int*)(ws + off);   off = align_up(off + NBINS * 4, 256);
    size_t zero_end = off;                            // memset deg..bins in one shot
    int*   binptr   = (int*)(ws + off);   off = align_up(off + NBINS * 4, 256);
    int*   row_ptr  = (int*)(ws + off);   off = align_up(off + (size_t)(n + 1) * 4, 256);
    int*   partials = (int*)(ws + off);   off = align_up(off + (size_t)nblk_nodes * 4, 256);
    float* dinvN    = (float*)(ws + off); off = align_up(off + (size_t)n * 4, 256);
    int*   order    = (int*)(ws + off);   off = align_up(off + (size_t)n * 4, 256);
    int*   cursor   = (int*)(ws + off);   off = align_up(off + (size_t)n * 4, 256);
    unsigned short* newid16 = (unsigned short*)(ws + off);
    off = align_up(off + (size_t)n * 2, 256);
    unsigned short* cs = (unsigned short*)(ws + off);
    off = align_up(off + (size_t)ne_pad_max * 2, 256);
    char*  p_base   = ws + off;
    (void)ws_size;                                    // 256MiB per harness evidence; needs ~110MB

    const int nbuf = 11;                              // p_0 .. p_10

    (void)hipMemsetAsync(deg, 0, zero_end, stream);   // deg + bins

    const int nblk_e4 = (ne / 4 + 255) / 256;        // 782 edge-chunk blocks
    count_deg<<<8 * nblk_e4, 256, 0, stream>>>(ei, deg, ne);

    // node renumbering by padded degree
    hist_deg<<<nblk_nodes, 256, 0, stream>>>(deg, bins, n);
    scan_bins<<<1, NBINS, 0, stream>>>(bins, binptr);
    scatter_order<<<nblk_nodes, 256, 0, stream>>>(deg, binptr, order, newid16, dinvN, n);

    scan1N<<<nblk_nodes, 256, 0, stream>>>(deg, order, row_ptr, partials, cursor, n);
    scan2<<<1, 256, 0, stream>>>(partials, nblk_nodes);
    scan3<<<nblk_nodes, 256, 0, stream>>>(row_ptr, partials, n);

    pad_fillN<<<nblk_nodes, 256, 0, stream>>>(cursor, row_ptr, cs, n);
    fill_csrN<<<8 * nblk_e4, 256, 0, stream>>>(ei, row_ptr, cursor, newid16, cs, ne);

    const int nlin = NSLICE * LANES_PER_SLICE + nbuf * NSLICE * SUBS;
    prescale16N<<<(nlin + 255) / 256, 256, 0, stream>>>(x, dinvN, order, p_base, nbuf);

    const int PROP_GRID = 8 * 391;                   // slice2 (2 XCDs) covers 782 chunks
    for (int k = 0; k < STEPS; ++k) {
        const char* pin  = p_base + (size_t)k * SLAB;
        char*       pout = p_base + (size_t)(k + 1) * SLAB;
        prop16<<<PROP_GRID, 256, 0, stream>>>(pin, pout, row_ptr, cs, dinvN);
    }
    const int nfin = NSLICE * LANES_PER_SLICE;
    finalizeN<<<(nfin + 255) / 256, 256, 0, stream>>>(p_base, x, dinvN, order, gamma, out);
}